// Round 1
// baseline (366.033 us; speedup 1.0000x reference)
//
#include <hip/hip_runtime.h>

// Velocity field exponentiation by scaling-and-squaring, circular (dft) bounds.
// v (2,128,128,128,3) fp32. STEPS=8. out = id + v_final.
// Structure: 8 ping-pong passes (global dep per step). Step1 fuses /256 scale,
// step8 fuses +grid epilogue. dims=128 -> wrap is &127.

#define DIMW 128
#define NVOX (2 * 128 * 128 * 128)   // B*D*H*W = 4,194,304 threads

__global__ __launch_bounds__(256) void sq_step(
    const float* __restrict__ vin, float* __restrict__ vout,
    float scale, int add_grid)
{
    int tid = blockIdx.x * 256 + threadIdx.x;           // < NVOX
    int x = tid & 127;
    int y = (tid >> 7) & 127;
    int z = (tid >> 14) & 127;
    int bb = tid & ~((1 << 21) - 1);                    // b * D*H*W

    size_t base = (size_t)tid * 3;
    float vz = vin[base + 0] * scale;
    float vy = vin[base + 1] * scale;
    float vx = vin[base + 2] * scale;

    float pz = (float)z + vz, py = (float)y + vy, px = (float)x + vx;
    float fz = floorf(pz), fy = floorf(py), fx = floorf(px);
    float wz1 = pz - fz, wy1 = py - fy, wx1 = px - fx;
    float wz0 = 1.0f - wz1, wy0 = 1.0f - wy1, wx0 = 1.0f - wx1;

    int iz0 = ((int)fz) & 127, iy0 = ((int)fy) & 127, ix0 = ((int)fx) & 127;
    int iz1 = (iz0 + 1) & 127, iy1 = (iy0 + 1) & 127, ix1 = (ix0 + 1) & 127;

    float wzy00 = wz0 * wy0, wzy01 = wz0 * wy1;
    float wzy10 = wz1 * wy0, wzy11 = wz1 * wy1;

    float oz = vz, oy = vy, ox = vx;                    // out = v + sum(w * v[corner])

#define CORNER(IZ, IY, IX, WW)                                          \
    {                                                                   \
        size_t lin = (size_t)(bb + ((IZ) << 14) + ((IY) << 7) + (IX)) * 3; \
        float w = (WW);                                                 \
        oz += w * (vin[lin + 0] * scale);                               \
        oy += w * (vin[lin + 1] * scale);                               \
        ox += w * (vin[lin + 2] * scale);                               \
    }

    CORNER(iz0, iy0, ix0, wzy00 * wx0)
    CORNER(iz0, iy0, ix1, wzy00 * wx1)
    CORNER(iz0, iy1, ix0, wzy01 * wx0)
    CORNER(iz0, iy1, ix1, wzy01 * wx1)
    CORNER(iz1, iy0, ix0, wzy10 * wx0)
    CORNER(iz1, iy0, ix1, wzy10 * wx1)
    CORNER(iz1, iy1, ix0, wzy11 * wx0)
    CORNER(iz1, iy1, ix1, wzy11 * wx1)
#undef CORNER

    if (add_grid) { oz += (float)z; oy += (float)y; ox += (float)x; }

    vout[base + 0] = oz;
    vout[base + 1] = oy;
    vout[base + 2] = ox;
}

extern "C" void kernel_launch(void* const* d_in, const int* in_sizes, int n_in,
                              void* d_out, int out_size, void* d_ws, size_t ws_size,
                              hipStream_t stream) {
    const float* vel = (const float*)d_in[0];
    float* out = (float*)d_out;
    float* ws  = (float*)d_ws;    // needs 50.3 MB (one field)

    dim3 grid(NVOX / 256), block(256);
    const float s = 1.0f / 256.0f;   // 1 / 2^STEPS

    // step 1: raw velocity (scaled on load) -> ws
    sq_step<<<grid, block, 0, stream>>>(vel, ws, s, 0);
    // steps 2..7: ping-pong ws <-> out
    sq_step<<<grid, block, 0, stream>>>(ws, out, 1.0f, 0);
    sq_step<<<grid, block, 0, stream>>>(out, ws, 1.0f, 0);
    sq_step<<<grid, block, 0, stream>>>(ws, out, 1.0f, 0);
    sq_step<<<grid, block, 0, stream>>>(out, ws, 1.0f, 0);
    sq_step<<<grid, block, 0, stream>>>(ws, out, 1.0f, 0);
    sq_step<<<grid, block, 0, stream>>>(out, ws, 1.0f, 0);
    // step 8: fused +grid epilogue -> d_out
    sq_step<<<grid, block, 0, stream>>>(ws, out, 1.0f, 1);
}